// Round 10
// baseline (152.392 us; speedup 1.0000x reference)
//
#include <hip/hip_runtime.h>
#include <hip/hip_fp16.h>
#include <math.h>

#define B_SZ 16
#define N_SZ 16384
#define T_FR 128      // frames per block -> 2048 blocks
#define NTHR 256      // 4 waves
#define NMEL 80
#define NCH  81
#define MAGS 129      // magT row stride in 16B units (odd -> bank-group spread)

typedef _Float16 h8  __attribute__((ext_vector_type(8)));
typedef _Float16 h4  __attribute__((ext_vector_type(4)));
typedef float    f4  __attribute__((ext_vector_type(4)));
static_assert(sizeof(h8) == 16, "h8 must be 4 VGPRs");

// Fragment-ordered coefficient tables, published by block (0,0) on iteration 0;
// g_tab/g_built persist across graph replays so iterations >=1 take the fast
// load path. Release/acquire (agent scope) pairing makes iteration 0 race-free:
// blocks either see g_built=1 (g_tab visible) or self-compute.
// Units 0..2047:   DFT A-frags: unit = ((wv*2+pol)*4+kk)*64 + ln
//                  value[j] = coef[bin=16wv+(ln&15)][k=kk*32+((ln>>4)&3)*8+j]
//                  pol0: wh[k]*cos(2pi*bin*k/128), pol1: -wh[k]*sin(...)
// Units 2048..2687: mel W^T A-frags: unit = 2048 + (jt*2+kkB)*64 + ln
//                  value[j] = W[bin=kkB*32+((ln>>4)&3)*8+j][melj=16jt+(ln&15)]
__device__ _Float16 g_tab[2688 * 8];
__device__ int g_built;   // zero-initialized at module load

// ---------------- main kernel (single launch; no build_tables node) ----------------
// 128 frames/block, 4 waves. Phase 1: wave owns bin group 16wv..16wv+15 for all
// 128 frames (64 MFMA). Phase 2: wave owns frame groups {wv, wv+4}, mel GEMM
// K=64, direct global stores merged to 16B (global_store_dwordx4, align 4).
// Mappings identical to the validated r4-r9 kernels.
__global__ __launch_bounds__(NTHR, 4) void melspec_kernel(const float* __restrict__ x,
                                                          float* __restrict__ out) {
  __shared__ __align__(16) float xs[T_FR + 128];         // fp32 window
  __shared__ __align__(16) _Float16 xh2[248 * 8];        // Hankel: unit n = x[n..n+7]
  __shared__ __align__(16) _Float16 magT[8 * MAGS * 8];  // bg-major, 129-unit rows
  // total 21504 B

  const int tid = threadIdx.x;
  const int t0  = blockIdx.x * T_FR;
  const int b   = blockIdx.y;
  const float* xrow = x + (size_t)b * N_SZ;

  const int wv = tid >> 6;       // wave id
  const int ln = tid & 63;
  const int lr = ln & 15;        // A-row / B-col / C-col
  const int lg = (ln >> 4) & 3;  // k-subgroup

  // ---- phase 0a: x window -> xs via float4 (the ONLY global reads of x) ----
  if (tid < (T_FR + 128) / 4) {
    const int gi4 = t0 + tid * 4;
    float4 v = {0.f, 0.f, 0.f, 0.f};
    if (gi4 < N_SZ) v = *(const float4*)(xrow + gi4);    // 4-aligned; all-or-none
    ((float4*)xs)[tid] = v;
  }

  // ---- coefficient fragments: fast load (iter>=1) or one-time self-build ----
  h8 aRe[4], aIm[4], aW[10];
  const int built = __hip_atomic_load(&g_built, __ATOMIC_ACQUIRE,
                                      __HIP_MEMORY_SCOPE_AGENT);
  const h8* tabv = (const h8*)g_tab;
  if (__builtin_expect(built, 1)) {
#pragma unroll
    for (int kk = 0; kk < 4; ++kk) {
      aRe[kk] = tabv[((wv * 2 + 0) * 4 + kk) * 64 + ln];
      aIm[kk] = tabv[((wv * 2 + 1) * 4 + kk) * 64 + ln];
    }
#pragma unroll
    for (int q = 0; q < 10; ++q) aW[q] = tabv[2048 + q * 64 + ln];
  } else {
    // self-build (same math as the retired build_tables -> identical values)
    const float w0 = 6.2831853071795864769f / 128.0f;    // 2*pi/128
    const int bin = 16 * wv + lr;
#pragma unroll
    for (int kk = 0; kk < 4; ++kk) {
      h8 re, im;
#pragma unroll
      for (int j = 0; j < 8; ++j) {
        const int k = kk * 32 + lg * 8 + j;
        const float wh = 0.5f - 0.5f * __cosf(w0 * (float)k);   // Hann
        float sv, cv;
        __sincosf(w0 * (float)((bin * k) & 127), &sv, &cv);     // exact angle mod 2pi
        re[j] = (_Float16)(wh * cv);
        im[j] = (_Float16)(-wh * sv);
      }
      aRe[kk] = re; aIm[kk] = im;
    }
    const float mlo = 1127.0f * logf(1.0f + 80.0f / 700.0f);
    const float mhi = 1127.0f * logf(1.0f + 7600.0f / 700.0f);
    const float dm  = (mhi - mlo) / 81.0f;
#pragma unroll
    for (int q = 0; q < 10; ++q) {
      const int jt = q >> 1, kkB = q & 1;
      const float lower = mlo + dm * (float)(16 * jt + lr);
      h8 w;
#pragma unroll
      for (int j = 0; j < 8; ++j) {
        const int b2 = kkB * 32 + lg * 8 + j;                   // 0..63
        const float m = 1127.0f * logf(1.0f + 125.0f * (float)b2 / 700.0f);
        const float ls = (m - lower) / dm;                      // bin0 -> w=0
        const float us = (lower + 2.0f * dm - m) / dm;
        w[j] = (_Float16)fmaxf(0.0f, fminf(ls, us));
      }
      aW[q] = w;
    }
    // block (0,0): publish the table + release the flag (agent scope)
    if (blockIdx.x == 0 && blockIdx.y == 0) {
      h8* tw = (h8*)g_tab;
#pragma unroll
      for (int kk = 0; kk < 4; ++kk) {
        tw[((wv * 2 + 0) * 4 + kk) * 64 + ln] = aRe[kk];
        tw[((wv * 2 + 1) * 4 + kk) * 64 + ln] = aIm[kk];
      }
#pragma unroll
      for (int q = 0; q < 10; ++q) tw[2048 + q * 64 + ln] = aW[q];
      __threadfence();
      __syncthreads();
      if (tid == 0)
        __hip_atomic_store(&g_built, 1, __ATOMIC_RELEASE, __HIP_MEMORY_SCOPE_AGENT);
    }
  }
  __syncthreads();

  // ---- phase 0b: Hankel fp16 units from LDS (8 ds_read_b32 + cvt each) ----
  if (tid < 248) {               // units 0..247 cover frame 127 + k 127
    h8 tmp;
#pragma unroll
    for (int j = 0; j < 8; ++j) tmp[j] = (_Float16)xs[tid + j];
    *(h8*)(xh2 + tid * 8) = tmp;
  }
  __syncthreads();

  // ---- phase 1: DFT + magnitude, all 128 frames of this wave's 16 bins ----
#pragma unroll
  for (int ft = 0; ft < 8; ++ft) {
    f4 cr = {0.f, 0.f, 0.f, 0.f};
    f4 ci = {0.f, 0.f, 0.f, 0.f};
#pragma unroll
    for (int kk = 0; kk < 4; ++kk) {
      // B[k][col=lr] = x[(16ft+lr) + k], k = kk*32+lg*8+j -> Hankel unit
      const h8 bb = *(const h8*)(xh2 + (16 * ft + 32 * kk + 8 * lg + lr) * 8);
      cr = __builtin_amdgcn_mfma_f32_16x16x32_f16(aRe[kk], bb, cr, 0, 0, 0);
      ci = __builtin_amdgcn_mfma_f32_16x16x32_f16(aIm[kk], bb, ci, 0, 0, 0);
    }
    // C: col=lr=frame-in-ft, row=4lg+v=bin-in-group; bin = 16wv+4lg+v
    h4 pk;
#pragma unroll
    for (int v = 0; v < 4; ++v) {
      const float re = cr[v], im = ci[v];
      pk[v] = (_Float16)__builtin_amdgcn_sqrtf(re * re + im * im);
    }
    const int bg = 2 * wv + (lg >> 1);                       // bin>>3
    *(h4*)(magT + ((bg * MAGS + 16 * ft + lr) * 8 + 4 * (lg & 1))) = pk;
  }
  __syncthreads();

  // ---- phase 2: mel GEMM (K=64) + 16B-merged direct global stores ----
  float* orow = out + ((size_t)b * N_SZ + t0) * NCH;
#pragma unroll
  for (int gi = 0; gi < 2; ++gi) {
    const int g = wv + 4 * gi;                               // frame group 16g..16g+15
    f4 acc[5];
    {
      const f4 z = {0.f, 0.f, 0.f, 0.f};
#pragma unroll
      for (int i = 0; i < 5; ++i) acc[i] = z;
    }
#pragma unroll
    for (int kkB = 0; kkB < 2; ++kkB) {
      // B[bin][col=lr]: frame = 16g+lr, bin-slice = kkB*32+lg*8+j -> row kkB*4+lg
      const h8 bb = *(const h8*)(magT + ((kkB * 4 + lg) * MAGS + 16 * g + lr) * 8);
#pragma unroll
      for (int jt = 0; jt < 5; ++jt)
        acc[jt] = __builtin_amdgcn_mfma_f32_16x16x32_f16(aW[jt * 2 + kkB], bb, acc[jt], 0, 0, 0);
    }
    // per lane: frame fr = 16g+lr; mels 16jt+4lg..+3 = one 16B store per jt
    const int fr = 16 * g + lr;
    float* frow = orow + (size_t)fr * NCH;
    if (lg == 0) frow[0] = xs[fr];                           // channel 0 = exact x
#pragma unroll
    for (int jt = 0; jt < 5; ++jt)
      __builtin_memcpy(frow + 1 + 16 * jt + 4 * lg, &acc[jt], 16);  // dwordx4, align 4
  }
}

extern "C" void kernel_launch(void* const* d_in, const int* in_sizes, int n_in,
                              void* d_out, int out_size, void* d_ws, size_t ws_size,
                              hipStream_t stream) {
  const float* x = (const float*)d_in[0];
  float* out = (float*)d_out;
  dim3 grid(N_SZ / T_FR, B_SZ);
  dim3 block(NTHR);
  hipLaunchKernelGGL(melspec_kernel, grid, block, 0, stream, x, out);
}

// Round 11
// 152.197 us; speedup vs baseline: 1.0013x; 1.0013x over previous
//
#include <hip/hip_runtime.h>
#include <hip/hip_fp16.h>
#include <math.h>

#define B_SZ 16
#define N_SZ 16384
#define T_FR 128      // frames per block -> 2048 blocks
#define NTHR 256      // 4 waves
#define NMEL 80
#define NCH  81
#define MAGS 129      // magT row stride in 16B units (odd -> bank-group spread)

typedef _Float16 h8  __attribute__((ext_vector_type(8)));
typedef _Float16 h4  __attribute__((ext_vector_type(4)));
typedef float    f4  __attribute__((ext_vector_type(4)));
static_assert(sizeof(h8) == 16, "h8 must be 4 VGPRs");

// Fragment-ordered coefficient tables, published by block (0,0) on iteration 0;
// g_tab/g_built persist across graph replays so iterations >=1 take the fast
// load path. Release/acquire (agent scope) pairing makes iteration 0 race-free:
// blocks either see g_built=1 (g_tab visible) or self-compute.
// Units 0..2047:   DFT A-frags: unit = ((wv*2+pol)*4+kk)*64 + ln
//                  value[j] = coef[bin=16wv+(ln&15)][k=kk*32+((ln>>4)&3)*8+j]
//                  pol0: wh[k]*cos(2pi*bin*k/128), pol1: -wh[k]*sin(...)
// Units 2048..2687: mel W^T A-frags: unit = 2048 + (jt*2+kkB)*64 + ln
//                  value[j] = W[bin=kkB*32+((ln>>4)&3)*8+j][melj=16jt+(ln&15)]
__device__ _Float16 g_tab[2688 * 8];
__device__ int g_built;   // zero-initialized at module load

// ---------------- main kernel (single launch; no build_tables node) ----------------
// 128 frames/block, 4 waves. Phase 1: wave owns bin group 16wv..16wv+15 for all
// 128 frames (64 MFMA). Phase 2: wave owns frame groups {wv, wv+4}, mel GEMM
// K=64, direct SCALAR global stores (validated v8 pattern; misaligned dwordx4
// measured 2.6x WORSE in r10 -- TA slow path). Mappings = validated r4-r9.
__global__ __launch_bounds__(NTHR, 4) void melspec_kernel(const float* __restrict__ x,
                                                          float* __restrict__ out) {
  __shared__ __align__(16) float xs[T_FR + 128];         // fp32 window
  __shared__ __align__(16) _Float16 xh2[248 * 8];        // Hankel: unit n = x[n..n+7]
  __shared__ __align__(16) _Float16 magT[8 * MAGS * 8];  // bg-major, 129-unit rows
  // total 21504 B

  const int tid = threadIdx.x;
  const int t0  = blockIdx.x * T_FR;
  const int b   = blockIdx.y;
  const float* xrow = x + (size_t)b * N_SZ;

  const int wv = tid >> 6;       // wave id
  const int ln = tid & 63;
  const int lr = ln & 15;        // A-row / B-col / C-col
  const int lg = (ln >> 4) & 3;  // k-subgroup

  // ---- phase 0a: x window -> xs via float4 (the ONLY global reads of x) ----
  if (tid < (T_FR + 128) / 4) {
    const int gi4 = t0 + tid * 4;
    float4 v = {0.f, 0.f, 0.f, 0.f};
    if (gi4 < N_SZ) v = *(const float4*)(xrow + gi4);    // 4-aligned; all-or-none
    ((float4*)xs)[tid] = v;
  }

  // ---- coefficient fragments: fast load (iter>=1) or one-time self-build ----
  h8 aRe[4], aIm[4], aW[10];
  const int built = __hip_atomic_load(&g_built, __ATOMIC_ACQUIRE,
                                      __HIP_MEMORY_SCOPE_AGENT);
  const h8* tabv = (const h8*)g_tab;
  if (__builtin_expect(built, 1)) {
#pragma unroll
    for (int kk = 0; kk < 4; ++kk) {
      aRe[kk] = tabv[((wv * 2 + 0) * 4 + kk) * 64 + ln];
      aIm[kk] = tabv[((wv * 2 + 1) * 4 + kk) * 64 + ln];
    }
#pragma unroll
    for (int q = 0; q < 10; ++q) aW[q] = tabv[2048 + q * 64 + ln];
  } else {
    // self-build (same math as the retired build_tables -> identical values)
    const float w0 = 6.2831853071795864769f / 128.0f;    // 2*pi/128
    const int bin = 16 * wv + lr;
#pragma unroll
    for (int kk = 0; kk < 4; ++kk) {
      h8 re, im;
#pragma unroll
      for (int j = 0; j < 8; ++j) {
        const int k = kk * 32 + lg * 8 + j;
        const float wh = 0.5f - 0.5f * __cosf(w0 * (float)k);   // Hann
        float sv, cv;
        __sincosf(w0 * (float)((bin * k) & 127), &sv, &cv);     // exact angle mod 2pi
        re[j] = (_Float16)(wh * cv);
        im[j] = (_Float16)(-wh * sv);
      }
      aRe[kk] = re; aIm[kk] = im;
    }
    const float mlo = 1127.0f * logf(1.0f + 80.0f / 700.0f);
    const float mhi = 1127.0f * logf(1.0f + 7600.0f / 700.0f);
    const float dm  = (mhi - mlo) / 81.0f;
#pragma unroll
    for (int q = 0; q < 10; ++q) {
      const int jt = q >> 1, kkB = q & 1;
      const float lower = mlo + dm * (float)(16 * jt + lr);
      h8 w;
#pragma unroll
      for (int j = 0; j < 8; ++j) {
        const int b2 = kkB * 32 + lg * 8 + j;                   // 0..63
        const float m = 1127.0f * logf(1.0f + 125.0f * (float)b2 / 700.0f);
        const float ls = (m - lower) / dm;                      // bin0 -> w=0
        const float us = (lower + 2.0f * dm - m) / dm;
        w[j] = (_Float16)fmaxf(0.0f, fminf(ls, us));
      }
      aW[q] = w;
    }
    // block (0,0): publish the table + release the flag (agent scope)
    if (blockIdx.x == 0 && blockIdx.y == 0) {
      h8* tw = (h8*)g_tab;
#pragma unroll
      for (int kk = 0; kk < 4; ++kk) {
        tw[((wv * 2 + 0) * 4 + kk) * 64 + ln] = aRe[kk];
        tw[((wv * 2 + 1) * 4 + kk) * 64 + ln] = aIm[kk];
      }
#pragma unroll
      for (int q = 0; q < 10; ++q) tw[2048 + q * 64 + ln] = aW[q];
      __threadfence();
      __syncthreads();
      if (tid == 0)
        __hip_atomic_store(&g_built, 1, __ATOMIC_RELEASE, __HIP_MEMORY_SCOPE_AGENT);
    }
  }
  __syncthreads();

  // ---- phase 0b: Hankel fp16 units from LDS (8 ds_read_b32 + cvt each) ----
  if (tid < 248) {               // units 0..247 cover frame 127 + k 127
    h8 tmp;
#pragma unroll
    for (int j = 0; j < 8; ++j) tmp[j] = (_Float16)xs[tid + j];
    *(h8*)(xh2 + tid * 8) = tmp;
  }
  __syncthreads();

  // ---- phase 1: DFT + magnitude, all 128 frames of this wave's 16 bins ----
#pragma unroll
  for (int ft = 0; ft < 8; ++ft) {
    f4 cr = {0.f, 0.f, 0.f, 0.f};
    f4 ci = {0.f, 0.f, 0.f, 0.f};
#pragma unroll
    for (int kk = 0; kk < 4; ++kk) {
      // B[k][col=lr] = x[(16ft+lr) + k], k = kk*32+lg*8+j -> Hankel unit
      const h8 bb = *(const h8*)(xh2 + (16 * ft + 32 * kk + 8 * lg + lr) * 8);
      cr = __builtin_amdgcn_mfma_f32_16x16x32_f16(aRe[kk], bb, cr, 0, 0, 0);
      ci = __builtin_amdgcn_mfma_f32_16x16x32_f16(aIm[kk], bb, ci, 0, 0, 0);
    }
    // C: col=lr=frame-in-ft, row=4lg+v=bin-in-group; bin = 16wv+4lg+v
    h4 pk;
#pragma unroll
    for (int v = 0; v < 4; ++v) {
      const float re = cr[v], im = ci[v];
      pk[v] = (_Float16)__builtin_amdgcn_sqrtf(re * re + im * im);
    }
    const int bg = 2 * wv + (lg >> 1);                       // bin>>3
    *(h4*)(magT + ((bg * MAGS + 16 * ft + lr) * 8 + 4 * (lg & 1))) = pk;
  }
  __syncthreads();

  // ---- phase 2: mel GEMM (K=64) + direct scalar global stores ----
  float* orow = out + ((size_t)b * N_SZ + t0) * NCH;
#pragma unroll
  for (int gi = 0; gi < 2; ++gi) {
    const int g = wv + 4 * gi;                               // frame group 16g..16g+15
    f4 acc[5];
    {
      const f4 z = {0.f, 0.f, 0.f, 0.f};
#pragma unroll
      for (int i = 0; i < 5; ++i) acc[i] = z;
    }
#pragma unroll
    for (int kkB = 0; kkB < 2; ++kkB) {
      // B[bin][col=lr]: frame = 16g+lr, bin-slice = kkB*32+lg*8+j -> row kkB*4+lg
      const h8 bb = *(const h8*)(magT + ((kkB * 4 + lg) * MAGS + 16 * g + lr) * 8);
#pragma unroll
      for (int jt = 0; jt < 5; ++jt)
        acc[jt] = __builtin_amdgcn_mfma_f32_16x16x32_f16(aW[jt * 2 + kkB], bb, acc[jt], 0, 0, 0);
    }
    // per lane: frame fr = 16g+lr, mels 16jt+4lg+v (scalar dword stores)
    const int fr = 16 * g + lr;
    float* frow = orow + (size_t)fr * NCH;
    if (lg == 0) frow[0] = xs[fr];                           // channel 0 = exact x
#pragma unroll
    for (int jt = 0; jt < 5; ++jt)
#pragma unroll
      for (int v = 0; v < 4; ++v)
        frow[1 + 16 * jt + 4 * lg + v] = acc[jt][v];         // melj = 16jt+4lg+v
  }
}

extern "C" void kernel_launch(void* const* d_in, const int* in_sizes, int n_in,
                              void* d_out, int out_size, void* d_ws, size_t ws_size,
                              hipStream_t stream) {
  const float* x = (const float*)d_in[0];
  float* out = (float*)d_out;
  dim3 grid(N_SZ / T_FR, B_SZ);
  dim3 block(NTHR);
  hipLaunchKernelGGL(melspec_kernel, grid, block, 0, stream, x, out);
}